// Round 8
// baseline (814.665 us; speedup 1.0000x reference)
//
#include <hip/hip_runtime.h>
#include <cfloat>
#include <cmath>

// GAT layer: B=4,S=256,N=257,E=256, IN=OUT=128, EDIM=16, all f32.
// R8 model: this broker slice is HBM-BW-capped at ~820 GB/s (3 structurally
// different agg kernels all ran at bytes/820GBs; occupancy/latency changes did
// nothing). Currency = HBM bytes. h = x@W is LINEAR, so scatter commutes with
// the GEMM: agg(h) = agg_x(x) @ W, and pq = h.aq = x.(W aq). => never
// materialize h in HBM. One mega-kernel, one block per (b,s):
//   A: pq/pt matvecs vs precomputed waq=W@a[:128], wat=W@a[128:256]
//   B: edge logits + masked softmax (in-block, alpha stays in LDS)
//   C: zero agg_x [272][130] f32 in LDS
//   D: scatter: agg_x[vt] += alpha*x[vs], agg_x[vs] += alpha*x[vt] (x from L2)
//   E: out = elu(agg_x @ W) via bf16x3 MFMA, W bf16 hi/lo pre-split in ws
// HBM: read x once (135 MB) + write out once (135 MB) vs previous 550 MB.
// Index semantics replicate JAX: logit gather zeroes idx<0; scatter uses
// where(mask, idx, 0) then NEGATIVE WRAP (-1 -> 256) — validated in R2.

#define BB 4
#define SS 256
#define NNODE 257
#define EE 256
#define DIN 128
#define DOUT 128
#define EDIMC 16
#define NMASK (BB * SS * EE)          // 262144
#define MROWS (BB * SS * NNODE)       // 263168

// ws layout (bytes):
#define WS_FLAG_OFF  0
#define WS_MASK_OFF  1024                      // 262144
#define WS_WTHI_OFF  266240                    // 32768
#define WS_WTLO_OFF  (WS_WTHI_OFF + 32768)     // 32768
#define WS_WAQ_OFF   (WS_WTLO_OFF + 32768)     // 512
#define WS_WAT_OFF   (WS_WAQ_OFF + 512)        // 512
#define WS_ALPHA_OFF (WS_WAT_OFF + 512)        // 1 MiB (fallback path only)
#define WS_NEEDED    (WS_ALPHA_OFF + NMASK * 4)

typedef __attribute__((ext_vector_type(8))) short bf16x8;
typedef __attribute__((ext_vector_type(4))) float f32x4;

__device__ __forceinline__ unsigned short f2bf(float f) {
    unsigned u = __float_as_uint(f);
    u += 0x7fff + ((u >> 16) & 1);           // RNE
    return (unsigned short)(u >> 16);
}
__device__ __forceinline__ float bf2f(unsigned short h) {
    return __uint_as_float((unsigned)h << 16);
}

// ------------------------------------------------------- mask dtype sniffing
__global__ void detect_mask_kernel(const unsigned int* __restrict__ m, int* flag) {
    unsigned int v = 0;
    for (int i = threadIdx.x; i < 256; i += 64) v |= m[i];
    int bad = (v > 1u) ? 1 : 0;
    bad = __any(bad) ? 1 : 0;
    if (threadIdx.x == 0) *flag = bad;
}

__global__ __launch_bounds__(256) void mask_canon_kernel(
        const int* __restrict__ m32, const unsigned char* __restrict__ m8,
        const int* __restrict__ flag, unsigned char* __restrict__ out) {
    const bool byteLayout = (*flag != 0);
    int i = blockIdx.x * 256 + threadIdx.x;
    if (i < NMASK) out[i] = byteLayout ? (m8[i] != 0) : (m32[i] != 0);
}

// ---------------------------------------------- W prep: bf16 split + matvecs
// wthi/wtlo: transposed bf16 hi/lo Wt[n][k]; waq = W@a[0:128], wat = W@a[128:256]
__global__ __launch_bounds__(256) void wprep_kernel(
        const float* __restrict__ W, const float* __restrict__ a,
        unsigned short* __restrict__ wthi, unsigned short* __restrict__ wtlo,
        float* __restrict__ waq, float* __restrict__ wat) {
    const int tid = threadIdx.x;
    for (int i = tid; i < DIN * DOUT; i += 256) {
        const int k = i >> 7, n = i & 127;
        const float w = W[i];
        const unsigned short hi = f2bf(w);
        const unsigned short lo = f2bf(w - bf2f(hi));
        wthi[n * DIN + k] = hi;
        wtlo[n * DIN + k] = lo;
    }
    if (tid < DIN) {
        const float* wr = W + tid * DOUT;
        float sq = 0.f, st = 0.f;
        for (int n = 0; n < DOUT; n += 4) {
            float4 w4 = *reinterpret_cast<const float4*>(wr + n);
            float4 aq = *reinterpret_cast<const float4*>(a + n);
            float4 at4 = *reinterpret_cast<const float4*>(a + DOUT + n);
            sq += w4.x * aq.x + w4.y * aq.y + w4.z * aq.z + w4.w * aq.w;
            st += w4.x * at4.x + w4.y * at4.y + w4.z * at4.z + w4.w * at4.w;
        }
        waq[tid] = sq;
        wat[tid] = st;
    }
}

// ---------------------------------------------------------------- MEGA
// one block per (b,s), 512 threads (8 waves). LDS 158.3 KB -> 1 block/CU.
#define PADR 130                 // agg_x row stride (floats): 2-way banks max
#define WTP  132                 // W-tile row stride (ushorts)
__global__ __launch_bounds__(512) void fused_kernel(
        const float* __restrict__ x, const int* __restrict__ eidx,
        const float* __restrict__ eattr, const unsigned char* __restrict__ emask,
        const float* __restrict__ a,
        const unsigned short* __restrict__ wthi,
        const unsigned short* __restrict__ wtlo,
        const float* __restrict__ waq, const float* __restrict__ wat,
        float* __restrict__ out) {
    __shared__ float aggx[272 * PADR];                 // 141,440 B
    __shared__ __align__(16) char ubuf[2 * 32 * WTP * 2];  // 16,896 B (union)
    // phase A-D view of ubuf:
    float* pq    = (float*)ubuf;                       // [257]
    float* pt    = pq + NNODE;                         // [257]
    float* alpha = pt + NNODE;                         // [256]
    int*   meta  = (int*)(alpha + EE);                 // [256]
    float* red   = (float*)(meta + EE);                // [8]
    int*   redi  = (int*)(red + 8);                    // [8]
    // phase E view:
    unsigned short* wtile = (unsigned short*)ubuf;     // [2][32*WTP]

    const int tid = threadIdx.x;
    const int lane = tid & 63, wv = tid >> 6;
    const int bs = blockIdx.x;
    const float* xp = x + (long)bs * NNODE * DIN;

    // ---- C: zero agg_x
    for (int i = tid; i < 272 * PADR; i += 512) aggx[i] = 0.f;

    // ---- A: pq/pt matvecs (streams the x panel, warming L2 for phase D)
    {
        const float wq0 = waq[lane], wq1 = waq[lane + 64];
        const float wt0 = wat[lane], wt1 = wat[lane + 64];
        for (int n = wv; n < NNODE; n += 8) {
            const float x0 = xp[n * DIN + lane];
            const float x1 = xp[n * DIN + lane + 64];
            float s = fmaf(x0, wq0, x1 * wq1);
            float t = fmaf(x0, wt0, x1 * wt1);
#pragma unroll
            for (int o = 32; o > 0; o >>= 1) {
                s += __shfl_xor(s, o);
                t += __shfl_xor(t, o);
            }
            if (lane == 0) { pq[n] = s; pt[n] = t; }
        }
    }
    __syncthreads();

    // ---- B: edge logits + masked softmax (waves 0-3; alpha/meta -> LDS)
    float val = 0.f; bool m = false;
    if (tid < EE) {
        const long eb = (long)bs * EE + tid;
        const int si = eidx[2 * eb];
        const int ti = eidx[2 * eb + 1];
        const float4* ea4 = reinterpret_cast<const float4*>(eattr + eb * EDIMC);
        float dea = 0.f;
#pragma unroll
        for (int j = 0; j < 4; ++j) {
            float4 u = ea4[j];
            const float4 av = *reinterpret_cast<const float4*>(a + 2 * DOUT + 4 * j);
            dea += u.x * av.x + u.y * av.y + u.z * av.z + u.w * av.w;
        }
        val = (si >= 0 ? pq[si] : 0.f) + (ti >= 0 ? pt[ti] : 0.f) + dea;
        val = val > 0.f ? val : 0.2f * val;            // leaky_relu(0.2)
        m = emask[eb] != 0;
        int vs = m ? si : 0; if (vs < 0) vs += NNODE;  // JAX negative wrap
        int vt = m ? ti : 0; if (vt < 0) vt += NNODE;
        meta[tid] = vs | (vt << 16);

        float wm = m ? val : -FLT_MAX;
        int anyv = m ? 1 : 0;
#pragma unroll
        for (int o = 32; o > 0; o >>= 1) {
            wm = fmaxf(wm, __shfl_xor(wm, o));
            anyv |= __shfl_xor(anyv, o);
        }
        if (lane == 0) { red[wv] = wm; redi[wv] = anyv; }
    }
    __syncthreads();
    if (tid < EE) {
        const float gmax = fmaxf(fmaxf(red[0], red[1]), fmaxf(red[2], red[3]));
        const int ganyv = redi[0] | redi[1] | redi[2] | redi[3];
        float ex = m ? expf(val - gmax) : 0.f;
        float sm = ex;
#pragma unroll
        for (int o = 32; o > 0; o >>= 1) sm += __shfl_xor(sm, o);
        __syncthreads();                   // red[] reuse for sums
        if (lane == 0) red[wv] = sm;
        __syncthreads();
        const float gsum = red[0] + red[1] + red[2] + red[3];
        alpha[tid] = ganyv ? ex / gsum : (1.0f / EE);
    } else {
        __syncthreads();
        __syncthreads();
    }
    __syncthreads();

    // ---- D: scatter x-rows into agg_x (x gathers are L2-hot from phase A)
    {
        const int eslot = tid >> 4;                    // 32 edges per round
        const int d0 = (tid & 15) * 8;                 // 8 dims per thread
        for (int e0 = 0; e0 < EE; e0 += 32) {
            const int e = e0 + eslot;
            const float al = alpha[e];
            if (al != 0.f) {
                const int pv = meta[e];
                const int vs = pv & 0xffff, vt = pv >> 16;
                const float* xs_ = xp + (long)vs * DIN + d0;
                const float* xt_ = xp + (long)vt * DIN + d0;
                const float4 s0 = *reinterpret_cast<const float4*>(xs_);
                const float4 s1 = *reinterpret_cast<const float4*>(xs_ + 4);
                const float4 t0 = *reinterpret_cast<const float4*>(xt_);
                const float4 t1 = *reinterpret_cast<const float4*>(xt_ + 4);
                float* rt_ = &aggx[vt * PADR + d0];
                float* rs_ = &aggx[vs * PADR + d0];
                atomicAdd(rt_ + 0, al * s0.x); atomicAdd(rt_ + 1, al * s0.y);
                atomicAdd(rt_ + 2, al * s0.z); atomicAdd(rt_ + 3, al * s0.w);
                atomicAdd(rt_ + 4, al * s1.x); atomicAdd(rt_ + 5, al * s1.y);
                atomicAdd(rt_ + 6, al * s1.z); atomicAdd(rt_ + 7, al * s1.w);
                atomicAdd(rs_ + 0, al * t0.x); atomicAdd(rs_ + 1, al * t0.y);
                atomicAdd(rs_ + 2, al * t0.z); atomicAdd(rs_ + 3, al * t0.w);
                atomicAdd(rs_ + 4, al * t1.x); atomicAdd(rs_ + 5, al * t1.y);
                atomicAdd(rs_ + 6, al * t1.z); atomicAdd(rs_ + 7, al * t1.w);
            }
        }
    }

    // ---- E: out = elu(agg_x @ W), bf16x3 MFMA, N in 4 chunks of 32 cols
    const int lrow = lane & 15;
    const int lk8 = (lane >> 4) * 8;
    const int qrow = (lane >> 4) * 4;
    float* ob = out + (long)bs * NNODE * DIN;
    for (int nc = 0; nc < 4; ++nc) {
        __syncthreads();   // nc=0: D done; nc>0: prior wtile reads done
        {   // stage W-tile bf16 hi/lo [32 n][128 k]
            const int nl = tid >> 4, k8 = (tid & 15) * 8;
            const int gn = nc * 32 + nl;
            *reinterpret_cast<uint4*>(&wtile[nl * WTP + k8]) =
                *reinterpret_cast<const uint4*>(&wthi[gn * DIN + k8]);
            *reinterpret_cast<uint4*>(&wtile[32 * WTP + nl * WTP + k8]) =
                *reinterpret_cast<const uint4*>(&wtlo[gn * DIN + k8]);
        }
        __syncthreads();
        for (int rt = wv; rt < 17; rt += 8) {          // 272 rows / 16
            f32x4 acc0 = {0.f, 0.f, 0.f, 0.f};
            f32x4 acc1 = {0.f, 0.f, 0.f, 0.f};
#pragma unroll
            for (int kt = 0; kt < 4; ++kt) {
                const float* ap = &aggx[(rt * 16 + lrow) * PADR + kt * 32 + lk8];
                float av[8];
                *reinterpret_cast<float4*>(&av[0]) =
                    *reinterpret_cast<const float4*>(ap);
                *reinterpret_cast<float4*>(&av[4]) =
                    *reinterpret_cast<const float4*>(ap + 4);
                bf16x8 Ah, Al;
#pragma unroll
                for (int j = 0; j < 8; ++j) {
                    const unsigned short hi = f2bf(av[j]);
                    Ah[j] = (short)hi;
                    Al[j] = (short)f2bf(av[j] - bf2f(hi));
                }
                const int bo = kt * 32 + lk8;
                bf16x8 Bh0 = *reinterpret_cast<const bf16x8*>(
                    &wtile[lrow * WTP + bo]);
                bf16x8 Bl0 = *reinterpret_cast<const bf16x8*>(
                    &wtile[32 * WTP + lrow * WTP + bo]);
                bf16x8 Bh1 = *reinterpret_cast<const bf16x8*>(
                    &wtile[(16 + lrow) * WTP + bo]);
                bf16x8 Bl1 = *reinterpret_cast<const bf16x8*>(
                    &wtile[32 * WTP + (16 + lrow) * WTP + bo]);
                acc0 = __builtin_amdgcn_mfma_f32_16x16x32_bf16(Ah, Bh0, acc0, 0, 0, 0);
                acc0 = __builtin_amdgcn_mfma_f32_16x16x32_bf16(Ah, Bl0, acc0, 0, 0, 0);
                acc0 = __builtin_amdgcn_mfma_f32_16x16x32_bf16(Al, Bh0, acc0, 0, 0, 0);
                acc1 = __builtin_amdgcn_mfma_f32_16x16x32_bf16(Ah, Bh1, acc1, 0, 0, 0);
                acc1 = __builtin_amdgcn_mfma_f32_16x16x32_bf16(Ah, Bl1, acc1, 0, 0, 0);
                acc1 = __builtin_amdgcn_mfma_f32_16x16x32_bf16(Al, Bh1, acc1, 0, 0, 0);
            }
#pragma unroll
            for (int r = 0; r < 4; ++r) {
                const int row = rt * 16 + qrow + r;
                if (row < NNODE) {
                    float v0 = acc0[r];
                    v0 = v0 > 0.f ? v0 : expm1f(v0);   // elu
                    ob[(long)row * DIN + nc * 32 + lrow] = v0;
                    float v1 = acc1[r];
                    v1 = v1 > 0.f ? v1 : expm1f(v1);
                    ob[(long)row * DIN + nc * 32 + 16 + lrow] = v1;
                }
            }
        }
    }
}

// ============================ fallback path (ws too small) ==================
__global__ __launch_bounds__(256) void gemm_kernel(const float* __restrict__ x,
                                                   const float* __restrict__ W,
                                                   float* __restrict__ h) {
    __shared__ float xs[32][132];
    __shared__ float wsh[32][132];
    const int tid = threadIdx.x;
    const long m0 = (long)blockIdx.x * 128;
    const int tm = tid >> 4, tn = tid & 15;
    const int mr = tm * 8, nr = tn * 8;
    float acc[8][8];
#pragma unroll
    for (int i = 0; i < 8; ++i)
#pragma unroll
        for (int j = 0; j < 8; ++j) acc[i][j] = 0.f;
    for (int kt = 0; kt < 4; ++kt) {
#pragma unroll
        for (int j = 0; j < 4; ++j) {
            int idx = j * 256 + tid;
            int row = idx >> 3, kq = idx & 7;
            float4 v = *reinterpret_cast<const float4*>(
                x + (m0 + row) * DIN + kt * 32 + kq * 4);
            xs[kq * 4 + 0][row] = v.x; xs[kq * 4 + 1][row] = v.y;
            xs[kq * 4 + 2][row] = v.z; xs[kq * 4 + 3][row] = v.w;
        }
#pragma unroll
        for (int j = 0; j < 4; ++j) {
            int idx = j * 256 + tid;
            int row = idx >> 5, nq = idx & 31;
            float4 v = *reinterpret_cast<const float4*>(
                W + (kt * 32 + row) * DOUT + nq * 4);
            *reinterpret_cast<float4*>(&wsh[row][nq * 4]) = v;
        }
        __syncthreads();
#pragma unroll
        for (int k = 0; k < 32; ++k) {
            float4 a0 = *reinterpret_cast<const float4*>(&xs[k][mr]);
            float4 a1 = *reinterpret_cast<const float4*>(&xs[k][mr + 4]);
            float4 b0 = *reinterpret_cast<const float4*>(&wsh[k][nr]);
            float4 b1 = *reinterpret_cast<const float4*>(&wsh[k][nr + 4]);
            float av[8] = {a0.x, a0.y, a0.z, a0.w, a1.x, a1.y, a1.z, a1.w};
            float bv[8] = {b0.x, b0.y, b0.z, b0.w, b1.x, b1.y, b1.z, b1.w};
#pragma unroll
            for (int i = 0; i < 8; ++i)
#pragma unroll
                for (int jj = 0; jj < 8; ++jj)
                    acc[i][jj] = fmaf(av[i], bv[jj], acc[i][jj]);
        }
        __syncthreads();
    }
#pragma unroll
    for (int i = 0; i < 8; ++i) {
        float* dst = h + (m0 + mr + i) * DOUT + nr;
        *reinterpret_cast<float4*>(dst) =
            make_float4(acc[i][0], acc[i][1], acc[i][2], acc[i][3]);
        *reinterpret_cast<float4*>(dst + 4) =
            make_float4(acc[i][4], acc[i][5], acc[i][6], acc[i][7]);
    }
}

__global__ __launch_bounds__(256) void alpha_kernel(
        const float* __restrict__ h, const int* __restrict__ eidx,
        const float* __restrict__ eattr, const unsigned char* __restrict__ emask,
        const float* __restrict__ a, float* __restrict__ alpha_out) {
    __shared__ float pq[NNODE], pt[NNODE];
    __shared__ float ae[EDIMC];
    __shared__ float red[4];
    __shared__ int redi[4];
    const int tid = threadIdx.x;
    const int bs = blockIdx.x;
    const int lane = tid & 63, wave = tid >> 6;
    if (tid < EDIMC) ae[tid] = a[2 * DOUT + tid];
    const float a0 = a[lane], a1 = a[lane + 64];
    const float a2 = a[128 + lane], a3 = a[192 + lane];
    const float* hb = h + (long)bs * NNODE * DIN;
    for (int n = wave; n < NNODE; n += 4) {
        const float* hr = hb + n * DIN;
        float v0 = hr[lane], v1 = hr[lane + 64];
        float s = v0 * a0 + v1 * a1;
        float t = v0 * a2 + v1 * a3;
#pragma unroll
        for (int o = 32; o > 0; o >>= 1) {
            s += __shfl_xor(s, o);
            t += __shfl_xor(t, o);
        }
        if (lane == 0) { pq[n] = s; pt[n] = t; }
    }
    __syncthreads();
    const long ebase = (long)bs * EE + tid;
    const int si = eidx[2 * ebase];
    const int ti = eidx[2 * ebase + 1];
    const float4* ea4 = reinterpret_cast<const float4*>(eattr + ebase * EDIMC);
    float dea = 0.f;
#pragma unroll
    for (int j = 0; j < 4; ++j) {
        float4 u = ea4[j];
        dea += u.x * ae[4 * j] + u.y * ae[4 * j + 1] +
               u.z * ae[4 * j + 2] + u.w * ae[4 * j + 3];
    }
    float val = (si >= 0 ? pq[si] : 0.f) + (ti >= 0 ? pt[ti] : 0.f) + dea;
    val = val > 0.f ? val : 0.2f * val;
    const bool m = emask[ebase] != 0;
    float wm = m ? val : -FLT_MAX;
    int anyv = m ? 1 : 0;
#pragma unroll
    for (int o = 32; o > 0; o >>= 1) {
        wm = fmaxf(wm, __shfl_xor(wm, o));
        anyv |= __shfl_xor(anyv, o);
    }
    if (lane == 0) { red[wave] = wm; redi[wave] = anyv; }
    __syncthreads();
    const float gmax = fmaxf(fmaxf(red[0], red[1]), fmaxf(red[2], red[3]));
    const int ganyv = redi[0] | redi[1] | redi[2] | redi[3];
    float ex = m ? expf(val - gmax) : 0.f;
    float sm = ex;
#pragma unroll
    for (int o = 32; o > 0; o >>= 1) sm += __shfl_xor(sm, o);
    __syncthreads();
    if (lane == 0) red[wave] = sm;
    __syncthreads();
    const float gsum = red[0] + red[1] + red[2] + red[3];
    alpha_out[ebase] = ganyv ? ex / gsum : (1.0f / EE);
}

#define DSL 16
#define PAD 17
__global__ __launch_bounds__(512) void agg_kernel(
        const float* __restrict__ h, const int* __restrict__ eidx,
        const unsigned char* __restrict__ emask, const float* __restrict__ alpha,
        float* __restrict__ out) {
    __shared__ float hs[NNODE * PAD];
    __shared__ float acc[NNODE * PAD];
    __shared__ float meta_a[EE];
    __shared__ int   meta_v[EE];
    const int tid = threadIdx.x;
    const int bs = blockIdx.x;
    const int dbase = blockIdx.y * DSL;
    const int slot = tid >> 4, d = tid & 15;
    const float* hb = h + (long)bs * NNODE * DIN + dbase;
    for (int i = tid; i < NNODE * 4; i += 512) {
        int row = i >> 2, q = i & 3;
        float4 v = *reinterpret_cast<const float4*>(hb + (long)row * DIN + q * 4);
        float* dst = &hs[row * PAD + q * 4];
        dst[0] = v.x; dst[1] = v.y; dst[2] = v.z; dst[3] = v.w;
    }
    for (int i = tid; i < NNODE * PAD; i += 512) acc[i] = 0.f;
    if (tid < EE) {
        const long eb = (long)bs * EE + tid;
        const int si = eidx[2 * eb];
        const int ti = eidx[2 * eb + 1];
        const bool m = emask[eb] != 0;
        int vs = m ? si : 0; if (vs < 0) vs += NNODE;
        int vt = m ? ti : 0; if (vt < 0) vt += NNODE;
        meta_a[tid] = alpha[eb];
        meta_v[tid] = vs | (vt << 16);
    }
    __syncthreads();
#pragma unroll 4
    for (int e0 = 0; e0 < EE; e0 += 32) {
        const int e = e0 + slot;
        const float al = meta_a[e];
        if (al != 0.f) {
            const int pv = meta_v[e];
            const int vs = pv & 0xffff, vt = pv >> 16;
            const float hsv = hs[vs * PAD + d];
            const float htv = hs[vt * PAD + d];
            atomicAdd(&acc[vt * PAD + d], al * hsv);
            atomicAdd(&acc[vs * PAD + d], al * htv);
        }
    }
    __syncthreads();
    float* ob = out + (long)bs * NNODE * DIN + dbase;
    for (int n = slot; n < NNODE; n += 32) {
        const float v = acc[n * PAD + d];
        ob[(long)n * DIN + d] = v > 0.f ? v : expm1f(v);
    }
}

// ---------------------------------------------------------------- launch
extern "C" void kernel_launch(void* const* d_in, const int* in_sizes, int n_in,
                              void* d_out, int out_size, void* d_ws, size_t ws_size,
                              hipStream_t stream) {
    const float* x     = (const float*)d_in[0];
    const int* eidx    = (const int*)d_in[1];
    const float* eattr = (const float*)d_in[2];
    /* d_in[3] node_mask: unused by the reference forward */
    const void* emraw  = d_in[4];
    const float* W     = (const float*)d_in[5];
    const float* a     = (const float*)d_in[6];
    float* out = (float*)d_out;

    char* ws = (char*)d_ws;
    int* flag            = (int*)(ws + WS_FLAG_OFF);
    unsigned char* mask8 = (unsigned char*)(ws + WS_MASK_OFF);
    unsigned short* wthi = (unsigned short*)(ws + WS_WTHI_OFF);
    unsigned short* wtlo = (unsigned short*)(ws + WS_WTLO_OFF);
    float* waq           = (float*)(ws + WS_WAQ_OFF);
    float* wat           = (float*)(ws + WS_WAT_OFF);
    float* alpha         = (float*)(ws + WS_ALPHA_OFF);

    detect_mask_kernel<<<1, 64, 0, stream>>>((const unsigned int*)emraw, flag);
    mask_canon_kernel<<<NMASK / 256, 256, 0, stream>>>(
        (const int*)emraw, (const unsigned char*)emraw, flag, mask8);

    if (ws_size >= (size_t)WS_NEEDED) {
        wprep_kernel<<<1, 256, 0, stream>>>(W, a, wthi, wtlo, waq, wat);
        fused_kernel<<<BB * SS, 512, 0, stream>>>(
            x, eidx, eattr, mask8, a, wthi, wtlo, waq, wat, out);
    } else {
        float* h = out;   // scratch aliasing the output buffer
        gemm_kernel<<<MROWS / 128, 256, 0, stream>>>(x, W, h);
        alpha_kernel<<<BB * SS, 256, 0, stream>>>(h, eidx, eattr, mask8, a, alpha);
        agg_kernel<<<dim3(BB * SS, 8), 512, 0, stream>>>(h, eidx, mask8, alpha, out);
    }
}